// Round 1
// 3759.679 us; speedup vs baseline: 1.9202x; 1.9202x over previous
//
#include <hip/hip_runtime.h>

// Gru2: L=2, HS=512, IN=512, B=64, S=1024, f32 in/out.
// Layers independent; r-gate unused; gates collapse to Wc=W1*W2+dW1*dW2,
// Uc=U1*U2+dU1*dU2, rows [z;n]. 64 persistent WGs = 2L x 8 row-slices x
// 4 batch-groups(16). Weights live in VGPR/AGPR as MFMA A-frags.
// Round-4 change: same-XCD L2-coherent exchange. Runtime XCC_ID handshake
// verifies each domain's 8 WGs share an XCD; if so, h exchange goes through
// the shared L2 (plain stores + sc0 loads / global_load_lds sc0 into LDS)
// and steps are signaled by an L2-executed atomic counter. Fallback keeps
// the old path at agent scope. Removes per-step HBM write-through
// (WRITE_SIZE had out 134MB + h 134MB; h now stays on-die).

#define HS 512
#define IN_DIM 512
#define BATCH 64
#define SEQ 1024
#define NB 16
#define NDOM 8
#define LDS_ROW 516  // floats per staged x batch row (2064B)
#define HROW 520     // shorts per staged h batch row (1040B, 16B aligned, pad kills 16-way bank conflict)

typedef __attribute__((ext_vector_type(8))) short bf16x8;
typedef __attribute__((ext_vector_type(4))) float f32x4;
typedef unsigned long long u64;
typedef unsigned int u32;
typedef unsigned short ushort_t;

__device__ __forceinline__ ushort_t f2bf(float f) {  // RNE
  u32 u = __float_as_uint(f);
  u += 0x7FFFu + ((u >> 16) & 1u);
  return (ushort_t)(u >> 16);
}
__device__ __forceinline__ float bf2f(ushort_t s) {
  return __uint_as_float(((u32)s) << 16);
}

// ---- prep: h slot0 (f32->bf16), zero counters + placement table ----
__global__ void gru_prep(const float* __restrict__ h0,
                         ushort_t* __restrict__ hbuf,
                         u32* __restrict__ cnt) {
  u32 tid = blockIdx.x * 256u + threadIdx.x;
  if (tid < 2u * BATCH * HS) hbuf[tid] = f2bf(h0[tid]);       // [l][b][k]
  if (tid < NDOM * (SEQ + 1) + 64u) cnt[tid] = 0u;
}

__global__ __launch_bounds__(256, 1) void gru_main(
    const float* __restrict__ x, float* __restrict__ out,
    const float* __restrict__ W1, const float* __restrict__ W2,
    const float* __restrict__ U1, const float* __restrict__ U2,
    const float* __restrict__ dW1, const float* __restrict__ dW2,
    const float* __restrict__ dU1, const float* __restrict__ dU2,
    const float* __restrict__ b1, const float* __restrict__ b2,
    ushort_t* __restrict__ hbuf, u32* __restrict__ cntws) {
  __shared__ __align__(16) float xlds[2][NB * LDS_ROW];   // 2 x 33KB double buffer
  __shared__ __align__(16) ushort_t hlds[NB * HROW];      // 16.6KB staged h[t]
  __shared__ u32 mode_sh;

  const int bid    = blockIdx.x;       // 0..63
  const int domain = bid & 7;
  const int slice  = bid >> 3;         // 0..7
  const int layer  = domain & 1;
  const int bg     = domain >> 1;
  const int bo     = bg * NB;
  const int tid    = threadIdx.x;
  const int lane   = tid & 63;
  const int wave   = tid >> 6;
  const int quad   = lane >> 4;
  const int ln     = lane & 15;
  const int hw     = slice * 64 + wave * 16;

  u32* const cnt = cntws + domain * (SEQ + 1);
  u32* const tab = cntws + NDOM * (SEQ + 1);

  // ---- one-time placement handshake: is this whole domain on one XCD? ----
  if (tid == 0) {
    u32 xcc;
    asm volatile("s_getreg_b32 %0, hwreg(HW_REG_XCC_ID)" : "=s"(xcc));
    __hip_atomic_store(&tab[domain * 8 + slice], 256u + xcc,
                       __ATOMIC_RELAXED, __HIP_MEMORY_SCOPE_AGENT);
    u32 vals[8];
    for (;;) {
      bool ready = true;
#pragma unroll
      for (int i = 0; i < 8; ++i) {
        vals[i] = __hip_atomic_load(&tab[domain * 8 + i],
                                    __ATOMIC_RELAXED, __HIP_MEMORY_SCOPE_AGENT);
        ready = ready && (vals[i] >= 256u);
      }
      if (ready) break;
      __builtin_amdgcn_s_sleep(8);
    }
    u32 m = 1u;
#pragma unroll
    for (int i = 1; i < 8; ++i) m = (vals[i] == vals[0]) ? m : 0u;
    mode_sh = m;
  }
  __syncthreads();
  const bool fast = (mode_sh != 0u);

  // --- combine weights into register-resident bf16 A-frags (A[m=ln][k=quad*8+j]) ---
  const float w1z = W1[layer*3+1], w1n = W1[layer*3+2];
  const float dw1z = dW1[layer*3+1], dw1n = dW1[layer*3+2];
  const float u1z = U1[layer*3+1], u1n = U1[layer*3+2];
  const float du1z = dU1[layer*3+1], du1n = dU1[layer*3+2];
  const int hrow_w = hw + ln;
  const float* W2r  = W2  + ((size_t)layer*HS + hrow_w) * IN_DIM;
  const float* dW2r = dW2 + ((size_t)layer*HS + hrow_w) * IN_DIM;
  const float* U2r  = U2  + ((size_t)layer*HS + hrow_w) * HS;
  const float* dU2r = dU2 + ((size_t)layer*HS + hrow_w) * HS;

  bf16x8 uf[2][16], wf[2][16];
#pragma unroll
  for (int kc = 0; kc < 16; ++kc) {
    const int off = kc*32 + quad*8;
#pragma unroll
    for (int i = 0; i < 8; ++i) {
      float w2 = W2r[off+i], dw2 = dW2r[off+i];
      float u2 = U2r[off+i], du2 = dU2r[off+i];
      wf[0][kc][i] = (short)f2bf(w1z*w2 + dw1z*dw2);
      wf[1][kc][i] = (short)f2bf(w1n*w2 + dw1n*dw2);
      uf[0][kc][i] = (short)f2bf(u1z*u2 + du1z*du2);
      uf[1][kc][i] = (short)f2bf(u1n*u2 + du1n*du2);
    }
  }
  float bz[4], bn[4];
#pragma unroll
  for (int r = 0; r < 4; ++r) {
    const int row = hw + quad*4 + r;
    bz[r] = b1[layer*1536 + 512  + row] + b2[layer*1536 + 512  + row];
    bn[r] = b1[layer*1536 + 1024 + row] + b2[layer*1536 + 1024 + row];
  }

  const int b_lane = bo + ln;
  const size_t slotsz = (size_t)2 * BATCH * HS;
  ushort_t* hl = hbuf + (size_t)layer * BATCH * HS;

  // --- stage x[0]: each wave loads 4 batches x 2 chunks of 1KB ---
#pragma unroll
  for (int i = 0; i < 8; ++i) {
    int bi = wave * 4 + (i >> 1), ch = i & 1;
    const float* g = x + ((size_t)(bo + bi) * SEQ) * IN_DIM + ch * 256 + lane * 4;
    __builtin_amdgcn_global_load_lds(
        (const __attribute__((address_space(1))) void*)g,
        (__attribute__((address_space(3))) void*)&xlds[0][bi * LDS_ROW + ch * 256],
        16, 0, 0);
  }
  asm volatile("s_waitcnt vmcnt(0)" ::: "memory");
  __syncthreads();

  if (fast) {
    // ================= FAST: same-XCD L2-coherent exchange =================
    for (int t = 0; t < SEQ; ++t) {
      if (t + 1 < SEQ) {
#pragma unroll
        for (int i = 0; i < 8; ++i) {
          int bi = wave * 4 + (i >> 1), ch = i & 1;
          const float* g = x + ((size_t)(bo + bi) * SEQ + (t + 1)) * IN_DIM + ch * 256 + lane * 4;
          __builtin_amdgcn_global_load_lds(
              (const __attribute__((address_space(1))) void*)g,
              (__attribute__((address_space(3))) void*)&xlds[(t + 1) & 1][bi * LDS_ROW + ch * 256],
              16, 0, 0);
        }
      }
      // x-projection (h-independent; overlaps producer lag)
      f32x4 accz = {0.f,0.f,0.f,0.f}, accn = {0.f,0.f,0.f,0.f};
      const float* xrow = &xlds[t & 1][ln * LDS_ROW];
#pragma unroll
      for (int kc = 0; kc < 16; ++kc) {
        f32x4 a = *(const f32x4*)(xrow + kc*32 + quad*8);
        f32x4 b = *(const f32x4*)(xrow + kc*32 + quad*8 + 4);
        union { u32 u[4]; bf16x8 v; } xv;
        xv.u[0] = (__float_as_uint(a[1]) & 0xFFFF0000u) | (__float_as_uint(a[0]) >> 16);
        xv.u[1] = (__float_as_uint(a[3]) & 0xFFFF0000u) | (__float_as_uint(a[2]) >> 16);
        xv.u[2] = (__float_as_uint(b[1]) & 0xFFFF0000u) | (__float_as_uint(b[0]) >> 16);
        xv.u[3] = (__float_as_uint(b[3]) & 0xFFFF0000u) | (__float_as_uint(b[2]) >> 16);
        accz = __builtin_amdgcn_mfma_f32_16x16x32_bf16(wf[0][kc], xv.v, accz, 0, 0, 0);
        accn = __builtin_amdgcn_mfma_f32_16x16x32_bf16(wf[1][kc], xv.v, accn, 0, 0, 0);
      }
      // poll step counter: sc0 load = L1-bypass, shared-L2 hit (~250cy RT)
      if (t > 0) {
        const u32* cp = cnt + t;
        u32 c;
        do {
          asm volatile("global_load_dword %0, %1, off sc0\n\t"
                       "s_waitcnt vmcnt(0)"
                       : "=&v"(c) : "v"(cp) : "memory");
        } while (c != 8u);
      }
      // pull h[t] (16 rows x 1KB) from shared L2 into LDS; 4 rows per wave
      const ushort_t* hsrc = hl + (size_t)(t & 1) * slotsz + (size_t)bo * HS;
#pragma unroll
      for (int r = 0; r < 4; ++r) {
        const int row = wave * 4 + r;
        const ushort_t* g = hsrc + (size_t)row * HS + lane * 8;
        __builtin_amdgcn_global_load_lds(
            (const __attribute__((address_space(1))) void*)g,
            (__attribute__((address_space(3))) void*)&hlds[row * HROW],
            16, 0, 1 /* sc0 */);
      }
      asm volatile("s_waitcnt vmcnt(0)" ::: "memory");
      __syncthreads();
      // recurrent matvec from LDS
      const ushort_t* hr = &hlds[ln * HROW];
#pragma unroll
      for (int kc = 0; kc < 16; ++kc) {
        bf16x8 hv = *(const bf16x8*)(hr + kc*32 + quad*8);
        accz = __builtin_amdgcn_mfma_f32_16x16x32_bf16(uf[0][kc], hv, accz, 0, 0, 0);
        accn = __builtin_amdgcn_mfma_f32_16x16x32_bf16(uf[1][kc], hv, accn, 0, 0, 0);
      }
      u64 hprev = *(const u64*)(hr + hw + quad*4);
      // epilogue
      u64 packed = 0;
      f32x4 hnew;
#pragma unroll
      for (int r = 0; r < 4; ++r) {
        float gz = accz[r] + bz[r];
        float gn = accn[r] + bn[r];
        float z  = 1.f / (1.f + __expf(-gz));
        float e2 = __expf(2.f * gn);
        float n  = (e2 - 1.f) / (e2 + 1.f);
        float hp = bf2f((ushort_t)(hprev >> (16 * r)));
        float hn = (1.f - z) * n + z * hp;
        hnew[r] = hn;
        packed |= ((u64)f2bf(hn)) << (16 * r);
      }
      *(u64*)(hl + (size_t)((t + 1) & 1) * slotsz
              + (size_t)b_lane * HS + hw + quad*4) = packed;   // plain -> shared L2
      if (layer == 1)
        *(f32x4*)(out + ((size_t)b_lane * SEQ + t) * HS + hw + quad*4) = hnew;
      if (t == SEQ - 1)
        *(f32x4*)(out + (size_t)BATCH * SEQ * HS
                  + ((size_t)layer * BATCH + b_lane) * HS + hw + quad*4) = hnew;
      // stores acked in L2, converge WG, then one L2-atomic increment
      asm volatile("s_waitcnt vmcnt(0)" ::: "memory");
      __syncthreads();
      if (tid == 0)
        __hip_atomic_fetch_add(cnt + (t + 1), 1u,
                               __ATOMIC_RELAXED, __HIP_MEMORY_SCOPE_WORKGROUP);
    }
  } else {
    // ================= SLOW fallback: agent scope via MALL =================
    for (int t = 0; t < SEQ; ++t) {
      if (t + 1 < SEQ) {
#pragma unroll
        for (int i = 0; i < 8; ++i) {
          int bi = wave * 4 + (i >> 1), ch = i & 1;
          const float* g = x + ((size_t)(bo + bi) * SEQ + (t + 1)) * IN_DIM + ch * 256 + lane * 4;
          __builtin_amdgcn_global_load_lds(
              (const __attribute__((address_space(1))) void*)g,
              (__attribute__((address_space(3))) void*)&xlds[(t + 1) & 1][bi * LDS_ROW + ch * 256],
              16, 0, 0);
        }
      }
      f32x4 accz = {0.f,0.f,0.f,0.f}, accn = {0.f,0.f,0.f,0.f};
      const float* xrow = &xlds[t & 1][ln * LDS_ROW];
#pragma unroll
      for (int kc = 0; kc < 16; ++kc) {
        f32x4 a = *(const f32x4*)(xrow + kc*32 + quad*8);
        f32x4 b = *(const f32x4*)(xrow + kc*32 + quad*8 + 4);
        union { u32 u[4]; bf16x8 v; } xv;
        xv.u[0] = (__float_as_uint(a[1]) & 0xFFFF0000u) | (__float_as_uint(a[0]) >> 16);
        xv.u[1] = (__float_as_uint(a[3]) & 0xFFFF0000u) | (__float_as_uint(a[2]) >> 16);
        xv.u[2] = (__float_as_uint(b[1]) & 0xFFFF0000u) | (__float_as_uint(b[0]) >> 16);
        xv.u[3] = (__float_as_uint(b[3]) & 0xFFFF0000u) | (__float_as_uint(b[2]) >> 16);
        accz = __builtin_amdgcn_mfma_f32_16x16x32_bf16(wf[0][kc], xv.v, accz, 0, 0, 0);
        accn = __builtin_amdgcn_mfma_f32_16x16x32_bf16(wf[1][kc], xv.v, accn, 0, 0, 0);
      }
      if (t > 0) {
        while (__hip_atomic_load(cnt + t, __ATOMIC_RELAXED,
                                 __HIP_MEMORY_SCOPE_AGENT) != 8u)
          __builtin_amdgcn_s_sleep(1);
      }
      const ushort_t* hsrc = hl + (size_t)(t & 1) * slotsz + (size_t)b_lane * HS;
#pragma unroll
      for (int kc = 0; kc < 16; ++kc) {
        const u64* hp = (const u64*)(hsrc + kc*32 + quad*8);
        union { u64 q[2]; bf16x8 v; } hu;
        hu.q[0] = __hip_atomic_load(hp,     __ATOMIC_RELAXED, __HIP_MEMORY_SCOPE_AGENT);
        hu.q[1] = __hip_atomic_load(hp + 1, __ATOMIC_RELAXED, __HIP_MEMORY_SCOPE_AGENT);
        accz = __builtin_amdgcn_mfma_f32_16x16x32_bf16(uf[0][kc], hu.v, accz, 0, 0, 0);
        accn = __builtin_amdgcn_mfma_f32_16x16x32_bf16(uf[1][kc], hu.v, accn, 0, 0, 0);
      }
      u64 hprev = __hip_atomic_load((const u64*)(hsrc + hw + quad*4),
                                    __ATOMIC_RELAXED, __HIP_MEMORY_SCOPE_AGENT);
      u64 packed = 0;
      f32x4 hnew;
#pragma unroll
      for (int r = 0; r < 4; ++r) {
        float gz = accz[r] + bz[r];
        float gn = accn[r] + bn[r];
        float z  = 1.f / (1.f + __expf(-gz));
        float e2 = __expf(2.f * gn);
        float n  = (e2 - 1.f) / (e2 + 1.f);
        float hp = bf2f((ushort_t)(hprev >> (16 * r)));
        float hn = (1.f - z) * n + z * hp;
        hnew[r] = hn;
        packed |= ((u64)f2bf(hn)) << (16 * r);
      }
      __hip_atomic_store((u64*)(hl + (size_t)((t + 1) & 1) * slotsz
                                + (size_t)b_lane * HS + hw + quad*4),
                         packed, __ATOMIC_RELAXED, __HIP_MEMORY_SCOPE_AGENT);
      if (layer == 1)
        *(f32x4*)(out + ((size_t)b_lane * SEQ + t) * HS + hw + quad*4) = hnew;
      if (t == SEQ - 1)
        *(f32x4*)(out + (size_t)BATCH * SEQ * HS
                  + ((size_t)layer * BATCH + b_lane) * HS + hw + quad*4) = hnew;
      asm volatile("s_waitcnt vmcnt(0)" ::: "memory");
      __syncthreads();
      if (tid == 0)
        __hip_atomic_fetch_add(cnt + (t + 1), 1u,
                               __ATOMIC_RELAXED, __HIP_MEMORY_SCOPE_AGENT);
    }
  }
}

extern "C" void kernel_launch(void* const* d_in, const int* in_sizes, int n_in,
                              void* d_out, int out_size, void* d_ws, size_t ws_size,
                              hipStream_t stream) {
  const float* x   = (const float*)d_in[0];
  const float* h0  = (const float*)d_in[1];
  const float* W1  = (const float*)d_in[2];
  const float* W2  = (const float*)d_in[3];
  const float* U1  = (const float*)d_in[4];
  const float* U2  = (const float*)d_in[5];
  const float* dW1 = (const float*)d_in[6];
  const float* dW2 = (const float*)d_in[7];
  const float* dU1 = (const float*)d_in[8];
  const float* dU2 = (const float*)d_in[9];
  const float* b1  = (const float*)d_in[10];
  const float* b2  = (const float*)d_in[11];

  char* ws = (char*)d_ws;
  ushort_t* hbuf = (ushort_t*)ws;                  // 256 KiB: 2 slots x [l][b][k] bf16
  u32*      cnt  = (u32*)(ws + 262144);            // 8 dom x 1025 counters + 64-entry xcd table

  gru_prep<<<257, 256, 0, stream>>>(h0, hbuf, cnt);
  gru_main<<<64, 256, 0, stream>>>(x, (float*)d_out,
                                   W1, W2, U1, U2, dW1, dW2, dU1, dU2, b1, b2,
                                   hbuf, cnt);
}